// Round 5
// baseline (495.968 us; speedup 1.0000x reference)
//
#include <hip/hip_runtime.h>
#include <hip/hip_cooperative_groups.h>

namespace cg = cooperative_groups;

#define NN 100000
#define NE 1600000
#define DD 128
#define BN_EPS 1e-5f

#define WSH 6                          // log2(window size)
#define WSZ 64                         // nodes per window
#define NWIN ((NN + WSZ - 1) / WSZ)    // 1563 windows
#define NWINP 2048                     // padded bin count
#define EPB 8192                       // edges per scatter segment
#define NSCAT ((NE + EPB - 1) / EPB)   // 196 scatter-role blocks
#define CAP 1536                       // per-window capacity (mean 1023, max ~1160)
#define MAXGRID 1024                   // 4 blocks/CU x 256 CU at 34.8KB LDS

typedef __attribute__((ext_vector_type(8))) short short8;
typedef __attribute__((ext_vector_type(4))) float floatx4;

__device__ __forceinline__ unsigned short f2bf(float f) {
    union { float f; unsigned u; } v; v.f = f;
    return (unsigned short)((v.u + 0x7FFFu + ((v.u >> 16) & 1u)) >> 16);
}
__device__ __forceinline__ float bf2f(unsigned short u) {
    union { unsigned u; float f; } v; v.u = ((unsigned)u) << 16;
    return v.f;
}

struct GinParams {
    const float* h; const int* src; const int* dst; const float* eps;
    const float* W1; const float* b1; const float* W2; const float* b2;
    const float* gamma; const float* beta;
    float* out;
    float* stats; int* wcnt;
    unsigned short* W1t; unsigned short* W2t;
    int* estage; unsigned short* xb; unsigned short* hb;
};

// ---------------------------------------------------------------------------
// ONE cooperative dispatch, 4 phases separated by grid.sync():
//  P0: zero wcnt/stats
//  PA: blocks [0,196) window-scatter (chunk reservation); rest: W->bf16
//      transpose + h->bf16 copy
//  PB: per-window {LDS permute + degree-sorted gather + 2-layer MFMA MLP +
//      BN partial stats}, windows grid-strided
//  PC: out = h + relu(BN(Y2))
// All phase bodies identical to the round-4 kernels; only the dispatch
// boundaries were removed. LDS: one 34816B arena, phase-A bins and phase-B
// xl/un union both live inside it.
// ---------------------------------------------------------------------------
template <bool HB>
__global__ __launch_bounds__(256, 4) void gin_mega_kernel(GinParams p)
{
    __shared__ __align__(16) char smem[34816];
    unsigned short* xl = (unsigned short*)smem;            // [64][136] bf16
    char* un = smem + 17408;                               // union region
    int* bins = (int*)smem;                                // phase-A view

    // phase-B views of the union region
    int* es   = (int*)un;                                  // [1536]
    int* cnt  = (int*)(un + 6144);                         // [64]
    int* beg  = (int*)(un + 6400);                         // [64]
    int* cur  = (int*)(un + 6656);                         // [64]
    int* dh   = (int*)(un + 6912);                         // [64]
    int* dcur = (int*)(un + 7168);                         // [64]
    unsigned char* order = (unsigned char*)(un + 7424);    // [64]
    unsigned short* wl = (unsigned short*)un;              // [64][136] bf16
    float* sred = (float*)un;                              // [128][16]
    float* qred = sred + 2048;                             // [128][16]

    cg::grid_group grid = cg::this_grid();
    const int t = threadIdx.x;
    const int bid = blockIdx.x;
    const int nb = gridDim.x;
    const int lane = t & 63;
    const int wv = t >> 6;
    const int m = lane & 15;
    const int hi = lane >> 4;

    // ---- P0: zero global cursors/stats ----
    int gi = bid * 256 + t;
    if (gi < NWINP) p.wcnt[gi] = 0;
    if (gi < 2 * DD) p.stats[gi] = 0.0f;
    grid.sync();

    // ---- PA ----
    if (bid < NSCAT) {
        for (int w = t; w < NWINP; w += 256) bins[w] = 0;
        __syncthreads();
        int base = bid * EPB;
        int ecnt = min(EPB, NE - base);
        for (int i = t; i < ecnt; i += 256)
            atomicAdd(&bins[p.dst[base + i] >> WSH], 1);
        __syncthreads();
        for (int w = t; w < NWIN; w += 256) {
            int c = bins[w];
            int gb = c ? atomicAdd(&p.wcnt[w], c) : 0;
            bins[w] = w * CAP + gb;   // running cursor
        }
        __syncthreads();
        for (int i = t; i < ecnt; i += 256) {
            int d = p.dst[base + i];
            int pos = atomicAdd(&bins[d >> WSH], 1);
            p.estage[pos] = (p.src[base + i] << WSH) | (d & (WSZ - 1));
        }
    } else {
        int tid0 = (bid - NSCAT) * 256 + t;
        int stride = (nb - NSCAT) * 256;
        for (int i = tid0; i < DD * DD; i += stride) {
            int n = i >> 7, k = i & 127;
            p.W1t[i] = f2bf(p.W1[k * DD + n]);
            p.W2t[i] = f2bf(p.W2[k * DD + n]);
        }
        if (HB) {
            const float4* h4 = (const float4*)p.h;
            ushort4* hb4 = (ushort4*)p.hb;
            for (int i = tid0; i < NN * (DD / 4); i += stride) {
                float4 v = h4[i];
                ushort4 o;
                o.x = f2bf(v.x); o.y = f2bf(v.y); o.z = f2bf(v.z); o.w = f2bf(v.w);
                hb4[i] = o;
            }
        }
    }
    grid.sync();

    // ---- PB ----
    const float sE = 1.0f + p.eps[0];
    const float4* h4 = (const float4*)p.h;
    const short8* hb8 = (const short8*)p.hb;
    const int c8 = t & 15;

    for (int wdx = bid; wdx < NWIN; wdx += nb) {
        __syncthreads();  // previous window's xl/sred reads complete
        if (t < 64) { cnt[t] = 0; dh[t] = 0; }
        __syncthreads();
        int n = min(p.wcnt[wdx], CAP);
        int wbase = wdx * CAP;
        for (int i = t; i < n; i += 256)
            atomicAdd(&cnt[p.estage[wbase + i] & (WSZ - 1)], 1);
        __syncthreads();
        if (t < 64) beg[t] = cnt[t];
        __syncthreads();
#pragma unroll
        for (int ofs = 1; ofs < 64; ofs <<= 1) {
            int u = (t < 64 && t >= ofs) ? beg[t - ofs] : 0;
            __syncthreads();
            if (t < 64) beg[t] += u;
            __syncthreads();
        }
        if (t < 64) {
            int ex = beg[t] - cnt[t];
            beg[t] = ex;
            cur[t] = ex;
            atomicAdd(&dh[min(cnt[t], 63)], 1);
        }
        __syncthreads();
        if (t < 64) dcur[t] = dh[t];
        __syncthreads();
#pragma unroll
        for (int ofs = 1; ofs < 64; ofs <<= 1) {
            int u = (t < 64 && t >= ofs) ? dcur[t - ofs] : 0;
            __syncthreads();
            if (t < 64) dcur[t] += u;
            __syncthreads();
        }
        if (t < 64) dcur[t] -= dh[t];
        __syncthreads();
        if (t < 64) {
            int pp = atomicAdd(&dcur[min(cnt[t], 63)], 1);
            order[pp] = (unsigned char)t;
        }
        __syncthreads();
        for (int i = t; i < n; i += 256) {
            int e = p.estage[wbase + i];
            int pp = atomicAdd(&cur[e & (WSZ - 1)], 1);
            es[pp] = e >> WSH;
        }
        __syncthreads();

        // gather (16 lanes/node, degree-sorted)
#pragma unroll
        for (int pass = 0; pass < 4; ++pass) {
            int nl = order[pass * 16 + (t >> 4)];
            int node = wdx * WSZ + nl;
            if (node >= NN) {
                short8 z = {0, 0, 0, 0, 0, 0, 0, 0};
                *(short8*)&xl[nl * 136 + c8 * 8] = z;
                continue;
            }
            float4 a0 = h4[node * 32 + c8 * 2];
            float4 a1 = h4[node * 32 + c8 * 2 + 1];
            float acc[8] = {sE * a0.x, sE * a0.y, sE * a0.z, sE * a0.w,
                            sE * a1.x, sE * a1.y, sE * a1.z, sE * a1.w};
            int e = beg[nl], eend = beg[nl] + cnt[nl];
            if (HB) {
                for (; e + 3 < eend; e += 4) {
                    int s0 = es[e], s1 = es[e + 1], s2 = es[e + 2], s3 = es[e + 3];
                    short8 v0 = hb8[s0 * 16 + c8];
                    short8 v1 = hb8[s1 * 16 + c8];
                    short8 v2 = hb8[s2 * 16 + c8];
                    short8 v3 = hb8[s3 * 16 + c8];
#pragma unroll
                    for (int j = 0; j < 8; ++j) {
                        float t0 = bf2f((unsigned short)v0[j]) + bf2f((unsigned short)v1[j]);
                        float t1 = bf2f((unsigned short)v2[j]) + bf2f((unsigned short)v3[j]);
                        acc[j] += t0 + t1;
                    }
                }
                for (; e < eend; ++e) {
                    short8 v0 = hb8[es[e] * 16 + c8];
#pragma unroll
                    for (int j = 0; j < 8; ++j) acc[j] += bf2f((unsigned short)v0[j]);
                }
            } else {
                for (; e + 1 < eend; e += 2) {
                    int s0 = es[e], s1 = es[e + 1];
                    float4 u0 = h4[s0 * 32 + c8 * 2], u1 = h4[s0 * 32 + c8 * 2 + 1];
                    float4 w0 = h4[s1 * 32 + c8 * 2], w1 = h4[s1 * 32 + c8 * 2 + 1];
                    acc[0] += u0.x + w0.x; acc[1] += u0.y + w0.y;
                    acc[2] += u0.z + w0.z; acc[3] += u0.w + w0.w;
                    acc[4] += u1.x + w1.x; acc[5] += u1.y + w1.y;
                    acc[6] += u1.z + w1.z; acc[7] += u1.w + w1.w;
                }
                if (e < eend) {
                    int s0 = es[e];
                    float4 u0 = h4[s0 * 32 + c8 * 2], u1 = h4[s0 * 32 + c8 * 2 + 1];
                    acc[0] += u0.x; acc[1] += u0.y; acc[2] += u0.z; acc[3] += u0.w;
                    acc[4] += u1.x; acc[5] += u1.y; acc[6] += u1.z; acc[7] += u1.w;
                }
            }
            short8 o;
#pragma unroll
            for (int j = 0; j < 8; ++j) o[j] = (short)f2bf(acc[j]);
            *(short8*)&xl[nl * 136 + c8 * 8] = o;
        }
        __syncthreads();  // xl complete; permute scratch dead -> wl

        // GEMM1: Y1 = relu(x@W1+b1), W half-staged
        floatx4 acc[8];
#pragma unroll
        for (int i = 0; i < 8; ++i) acc[i] = (floatx4){0.f, 0.f, 0.f, 0.f};
        const short8* W1t8 = (const short8*)p.W1t;
#pragma unroll
        for (int hh = 0; hh < 2; ++hh) {
#pragma unroll
            for (int l = 0; l < 4; ++l) {
                int idx = t + l * 256;
                int nr = idx >> 4, c = idx & 15;
                *(short8*)&wl[nr * 136 + c * 8] = W1t8[(hh * 64 + nr) * 16 + c];
            }
            __syncthreads();
#pragma unroll
            for (int kc = 0; kc < 4; ++kc) {
                short8 a = *(const short8*)&xl[(wv * 16 + m) * 136 + kc * 32 + hi * 8];
#pragma unroll
                for (int ntl = 0; ntl < 4; ++ntl) {
                    short8 bb = *(const short8*)&wl[(ntl * 16 + m) * 136 + kc * 32 + hi * 8];
                    acc[hh * 4 + ntl] =
                        __builtin_amdgcn_mfma_f32_16x16x32_bf16(a, bb, acc[hh * 4 + ntl], 0, 0, 0);
                }
            }
            __syncthreads();
        }
#pragma unroll
        for (int nt = 0; nt < 8; ++nt) {
            float bv = p.b1[nt * 16 + m];
#pragma unroll
            for (int r = 0; r < 4; ++r) {
                float v = fmaxf(acc[nt][r] + bv, 0.f);
                xl[(wv * 16 + hi * 4 + r) * 136 + nt * 16 + m] = f2bf(v);
            }
        }
        __syncthreads();

        // GEMM2: Y2 = Y1@W2+b2
#pragma unroll
        for (int i = 0; i < 8; ++i) acc[i] = (floatx4){0.f, 0.f, 0.f, 0.f};
        const short8* W2t8 = (const short8*)p.W2t;
#pragma unroll
        for (int hh = 0; hh < 2; ++hh) {
#pragma unroll
            for (int l = 0; l < 4; ++l) {
                int idx = t + l * 256;
                int nr = idx >> 4, c = idx & 15;
                *(short8*)&wl[nr * 136 + c * 8] = W2t8[(hh * 64 + nr) * 16 + c];
            }
            __syncthreads();
#pragma unroll
            for (int kc = 0; kc < 4; ++kc) {
                short8 a = *(const short8*)&xl[(wv * 16 + m) * 136 + kc * 32 + hi * 8];
#pragma unroll
                for (int ntl = 0; ntl < 4; ++ntl) {
                    short8 bb = *(const short8*)&wl[(ntl * 16 + m) * 136 + kc * 32 + hi * 8];
                    acc[hh * 4 + ntl] =
                        __builtin_amdgcn_mfma_f32_16x16x32_bf16(a, bb, acc[hh * 4 + ntl], 0, 0, 0);
                }
            }
            __syncthreads();
        }

        // Y2 -> xl (bf16) + BN partials from f32 accumulators
#pragma unroll
        for (int nt = 0; nt < 8; ++nt) {
            float bv = p.b2[nt * 16 + m];
            float ss = 0.f, qq = 0.f;
#pragma unroll
            for (int r = 0; r < 4; ++r) {
                int row = wv * 16 + hi * 4 + r;
                float v = acc[nt][r] + bv;
                xl[row * 136 + nt * 16 + m] = f2bf(v);
                if (wdx * WSZ + row < NN) { ss += v; qq += v * v; }
            }
            sred[(nt * 16 + m) * 16 + wv * 4 + hi] = ss;
            qred[(nt * 16 + m) * 16 + wv * 4 + hi] = qq;
        }
        __syncthreads();

#pragma unroll
        for (int l = 0; l < 4; ++l) {
            int idx = t + l * 256;
            int row = idx >> 4, c = idx & 15;
            int g = wdx * WSZ + row;
            if (g < NN)
                ((short8*)p.xb)[g * 16 + c] = *(const short8*)&xl[row * 136 + c * 8];
        }
        if (t < 128) {
            float s = 0.f, q = 0.f;
#pragma unroll
            for (int j = 0; j < 16; ++j) { s += sred[t * 16 + j]; q += qred[t * 16 + j]; }
            atomicAdd(&p.stats[t], s);
            atomicAdd(&p.stats[DD + t], q);
        }
    }
    grid.sync();

    // ---- PC: out = h + relu(Y2*scale + shift) ----
    {
        const float invN = 1.0f / (float)NN;
        int t0 = bid * 256 + t;
        int cc = t0 & 15;
        float sc[8], sh[8];
#pragma unroll
        for (int j = 0; j < 8; ++j) {
            int col = cc * 8 + j;
            float mu = p.stats[col] * invN;
            float var = p.stats[DD + col] * invN - mu * mu;
            float s = rsqrtf(var + BN_EPS) * p.gamma[col];
            sc[j] = s;
            sh[j] = p.beta[col] - mu * s;
        }
        const short8* Y8 = (const short8*)p.xb;
        const float4* H4 = (const float4*)p.h;
        float4* O4 = (float4*)p.out;
        const int total = NN * 16;
        const int stride = nb * 256;   // multiple of 16 -> column octet fixed
        for (int i = t0; i < total; i += stride) {
            short8 u = Y8[i];
            float4 h0 = H4[2 * i], h1 = H4[2 * i + 1];
            float4 r0, r1;
            r0.x = h0.x + fmaxf(bf2f((unsigned short)u[0]) * sc[0] + sh[0], 0.f);
            r0.y = h0.y + fmaxf(bf2f((unsigned short)u[1]) * sc[1] + sh[1], 0.f);
            r0.z = h0.z + fmaxf(bf2f((unsigned short)u[2]) * sc[2] + sh[2], 0.f);
            r0.w = h0.w + fmaxf(bf2f((unsigned short)u[3]) * sc[3] + sh[3], 0.f);
            r1.x = h1.x + fmaxf(bf2f((unsigned short)u[4]) * sc[4] + sh[4], 0.f);
            r1.y = h1.y + fmaxf(bf2f((unsigned short)u[5]) * sc[5] + sh[5], 0.f);
            r1.z = h1.z + fmaxf(bf2f((unsigned short)u[6]) * sc[6] + sh[6], 0.f);
            r1.w = h1.w + fmaxf(bf2f((unsigned short)u[7]) * sc[7] + sh[7], 0.f);
            O4[2 * i] = r0;
            O4[2 * i + 1] = r1;
        }
    }
}

// ---------------------------------------------------------------------------
extern "C" void kernel_launch(void* const* d_in, const int* in_sizes, int n_in,
                              void* d_out, int out_size, void* d_ws, size_t ws_size,
                              hipStream_t stream)
{
    GinParams prm;
    prm.h     = (const float*)d_in[0];
    prm.src   = (const int*)d_in[1];
    prm.dst   = (const int*)d_in[2];
    prm.eps   = (const float*)d_in[3];
    prm.W1    = (const float*)d_in[4];
    prm.b1    = (const float*)d_in[5];
    prm.W2    = (const float*)d_in[6];
    prm.b2    = (const float*)d_in[7];
    prm.gamma = (const float*)d_in[8];
    prm.beta  = (const float*)d_in[9];
    prm.out   = (float*)d_out;

    char* w = (char*)d_ws;
    size_t o = 0;
    prm.stats  = (float*)(w + o); o += 256 * 4;
    prm.wcnt   = (int*)(w + o); o += NWINP * 4;
    prm.W1t    = (unsigned short*)(w + o); o += (size_t)DD * DD * 2;
    prm.W2t    = (unsigned short*)(w + o); o += (size_t)DD * DD * 2;
    prm.estage = (int*)(w + o); o += (size_t)NWIN * CAP * 4;    // 9.6 MB
    prm.xb     = (unsigned short*)(w + o); o += (size_t)NN * DD * 2;
    prm.hb     = (unsigned short*)(w + o); o += (size_t)NN * DD * 2;
    const int use_hb = (ws_size >= o) ? 1 : 0;

    int maxb = 0;
    if (use_hb)
        hipOccupancyMaxActiveBlocksPerMultiprocessor(&maxb, gin_mega_kernel<true>, 256, 0);
    else
        hipOccupancyMaxActiveBlocksPerMultiprocessor(&maxb, gin_mega_kernel<false>, 256, 0);
    if (maxb <= 0) maxb = 4;
    int grid = maxb * 256;
    if (grid > MAXGRID) grid = MAXGRID;
    if (grid < 256) grid = 256;   // need >=196 scatter + some prep blocks

    void* kargs[] = { &prm };
    if (use_hb)
        hipLaunchCooperativeKernel(reinterpret_cast<void*>(gin_mega_kernel<true>),
                                   dim3(grid), dim3(256), kargs, 0, stream);
    else
        hipLaunchCooperativeKernel(reinterpret_cast<void*>(gin_mega_kernel<false>),
                                   dim3(grid), dim3(256), kargs, 0, stream);
}

// Round 6
// 287.220 us; speedup vs baseline: 1.7268x; 1.7268x over previous
//
#include <hip/hip_runtime.h>

#define NN 100000
#define NE 1600000
#define DD 128
#define BN_EPS 1e-5f

#define SBSH 9                         // log2(super-bucket size)
#define SBSZ 512                       // nodes per super-bucket
#define NSB ((NN + SBSZ - 1) / SBSZ)   // 196 super-buckets
#define CAPS 9216                      // slots per super-bucket (mean 8192, sigma ~90 -> +11 sigma)
#define EPB 8192                       // edges per pass-1 block
#define NBLK ((NE + EPB - 1) / EPB)    // 196 pass-1 scatter blocks
#define PREPBLKS 828
#define GRID_PS (NBLK + PREPBLKS)      // 1024
#define TSZ 64                         // nodes per gather/MLP tile
#define NTILE ((NN + TSZ - 1) / TSZ)   // 1563
#define BN_BLOCKS 1024

typedef __attribute__((ext_vector_type(8))) short short8;
typedef __attribute__((ext_vector_type(4))) float floatx4;

__device__ __forceinline__ unsigned short f2bf(float f) {
    union { float f; unsigned u; } v; v.f = f;
    return (unsigned short)((v.u + 0x7FFFu + ((v.u >> 16) & 1u)) >> 16);
}
__device__ __forceinline__ float bf2f(unsigned short u) {
    union { unsigned u; float f; } v; v.u = ((unsigned)u) << 16;
    return v.f;
}

// ---------------------------------------------------------------------------
// K1 (fused): blocks [0,196) = pass-1 radix: LDS bucket-sort 8192 edges into
// 196 super-buckets (dst>>9) and copy contiguous ~42-int runs (~2.6 cache
// lines) to reserved chunks in sbuf -> sequential, write-combined, no
// cross-XCD ping-pong. Blocks [196,1024) = prep (W->bf16 transpose, h->bf16).
// scnt must be zeroed by the preceding hipMemsetAsync.
// ---------------------------------------------------------------------------
__global__ __launch_bounds__(256) void prep_scatter_kernel(
    const float* __restrict__ W1, const float* __restrict__ W2,
    unsigned short* __restrict__ W1t, unsigned short* __restrict__ W2t,
    const float* __restrict__ h, unsigned short* __restrict__ hb, int do_hb,
    const int* __restrict__ src, const int* __restrict__ dst,
    int* __restrict__ scnt, int* __restrict__ sbuf)
{
    __shared__ int bins[256];     // count -> cursor -> run end
    __shared__ int lofs[256];     // run begin
    __shared__ int gbase[256];    // reserved global base
    __shared__ int stmp[256];
    __shared__ int sorted[EPB];   // 32 KB
    int t = threadIdx.x;

    if (blockIdx.x < NBLK) {
        bins[t] = 0;
        __syncthreads();
        int base = blockIdx.x * EPB;
        int ecnt = min(EPB, NE - base);
        for (int i = t; i < ecnt; i += 256)
            atomicAdd(&bins[dst[base + i] >> SBSH], 1);
        __syncthreads();
        int c = bins[t];
        stmp[t] = c;
        __syncthreads();
#pragma unroll
        for (int ofs = 1; ofs < 256; ofs <<= 1) {
            int u = (t >= ofs) ? stmp[t - ofs] : 0;
            __syncthreads();
            stmp[t] += u;
            __syncthreads();
        }
        int excl = stmp[t] - c;
        lofs[t] = excl;
        int gb = (t < NSB && c) ? atomicAdd(&scnt[t], c) : 0;
        gbase[t] = t * CAPS + gb;
        bins[t] = excl;           // cursor for the sort pass
        __syncthreads();

        for (int i = t; i < ecnt; i += 256) {
            int d = dst[base + i];
            int p = atomicAdd(&bins[d >> SBSH], 1);
            sorted[p] = (src[base + i] << SBSH) | (d & (SBSZ - 1));
        }
        __syncthreads();

        // copy contiguous runs (bins[sb] is now run end)
        for (int sb = t; sb < NSB; sb += 256) {
            int lb = lofs[sb], le = bins[sb];
            int g = gbase[sb];
            for (int j = lb; j < le; ++j)
                sbuf[g + (j - lb)] = sorted[j];
        }
    } else {
        int tid0 = (blockIdx.x - NBLK) * 256 + t;
        int stride = PREPBLKS * 256;
        for (int i = tid0; i < DD * DD; i += stride) {
            int n = i >> 7, k = i & 127;
            W1t[i] = f2bf(W1[k * DD + n]);
            W2t[i] = f2bf(W2[k * DD + n]);
        }
        if (do_hb) {
            const float4* h4 = (const float4*)h;
            ushort4* hb4 = (ushort4*)hb;
            for (int i = tid0; i < NN * (DD / 4); i += stride) {
                float4 v = h4[i];
                ushort4 o;
                o.x = f2bf(v.x); o.y = f2bf(v.y); o.z = f2bf(v.z); o.w = f2bf(v.w);
                hb4[i] = o;
            }
        }
    }
}

// ---------------------------------------------------------------------------
// K2: pass-2 permute. One 512-thread block per super-bucket: stage ~8.2K
// entries in LDS, per-node count+scan, write off2[node]={beg,end} (absolute),
// permute src indices IN PLACE into sbuf. Random writes confined to a 36KB
// single-writer region -> one XCD's L2, no fabric ping-pong.
// ---------------------------------------------------------------------------
__global__ __launch_bounds__(512) void permute_kernel(
    const int* __restrict__ scnt, int* __restrict__ sbuf,
    int2* __restrict__ off2)
{
    __shared__ int ew[CAPS];          // 36864 B
    __shared__ int cnt[SBSZ];
    __shared__ int beg[SBSZ];
    __shared__ int cur[SBSZ];
    __shared__ int stmp[512];
    int sb = blockIdx.x, t = threadIdx.x;
    cnt[t] = 0;
    __syncthreads();
    int n = min(scnt[sb], CAPS);
    int sbase = sb * CAPS;
    for (int i = t; i < n; i += 512) {
        int e = sbuf[sbase + i];
        ew[i] = e;
        atomicAdd(&cnt[e & (SBSZ - 1)], 1);
    }
    __syncthreads();
    int c = cnt[t];
    stmp[t] = c;
    __syncthreads();
#pragma unroll
    for (int ofs = 1; ofs < 512; ofs <<= 1) {
        int u = (t >= ofs) ? stmp[t - ofs] : 0;
        __syncthreads();
        stmp[t] += u;
        __syncthreads();
    }
    int excl = stmp[t] - c;
    beg[t] = excl;
    cur[t] = excl;
    off2[sb * SBSZ + t] = make_int2(sbase + excl, sbase + excl + c);
    __syncthreads();
    for (int i = t; i < n; i += 512) {
        int e = ew[i];
        int p = atomicAdd(&cur[e & (SBSZ - 1)], 1);
        sbuf[sbase + p] = e >> SBSH;   // in place: all entries staged in LDS
    }
}

// ---------------------------------------------------------------------------
// K3: gather + 2-layer MFMA MLP + BN partial stats (round-4 body, permute
// phase deleted). 64-node tiles, degree-sorted gather (16 lanes/node), src
// indices read from global CSR (L2; 16 lanes broadcast the same address).
// ---------------------------------------------------------------------------
template <bool HB>
__global__ __launch_bounds__(256) void gather_mlp_kernel(
    const float* __restrict__ h, const unsigned short* __restrict__ hb,
    const float* __restrict__ eps, const int2* __restrict__ off2,
    const int* __restrict__ srcs,
    const unsigned short* __restrict__ W1t, const unsigned short* __restrict__ W2t,
    const float* __restrict__ b1, const float* __restrict__ b2,
    unsigned short* __restrict__ Y, float* __restrict__ stats)
{
    __shared__ __align__(16) unsigned short xl[TSZ * 136];  // 17408 B
    __shared__ __align__(16) char un[17408];                // union region

    int* beg64 = (int*)un;                     // [64]
    int* cnt64 = (int*)(un + 256);             // [64]
    int* dh    = (int*)(un + 512);             // [64]
    int* dcur  = (int*)(un + 768);             // [64]
    unsigned char* order = (unsigned char*)(un + 1024);  // [64]
    unsigned short* wl = (unsigned short*)un;  // GEMM-phase view
    float* sred = (float*)un;                  // [128][16]
    float* qred = sred + 2048;

    const int b = blockIdx.x;
    const int t = threadIdx.x;
    const int lane = t & 63;
    const int wv = t >> 6;
    const int m = lane & 15;
    const int hi = lane >> 4;

    // ---- per-node offsets + degree sort ----
    if (t < 64) dh[t] = 0;
    __syncthreads();
    if (t < 64) {
        int2 oo = off2[b * TSZ + t];           // b*64+t < NSB*SBSZ always
        beg64[t] = oo.x;
        cnt64[t] = oo.y - oo.x;
        atomicAdd(&dh[min(cnt64[t], 63)], 1);
    }
    __syncthreads();
    if (t < 64) dcur[t] = dh[t];
    __syncthreads();
#pragma unroll
    for (int ofs = 1; ofs < 64; ofs <<= 1) {
        int u = (t < 64 && t >= ofs) ? dcur[t - ofs] : 0;
        __syncthreads();
        if (t < 64) dcur[t] += u;
        __syncthreads();
    }
    if (t < 64) dcur[t] -= dh[t];
    __syncthreads();
    if (t < 64) {
        int p = atomicAdd(&dcur[min(cnt64[t], 63)], 1);
        order[p] = (unsigned char)t;
    }
    __syncthreads();

    // ---- gather (16 lanes/node, degree-sorted) ----
    const float sE = 1.0f + eps[0];
    const float4* h4 = (const float4*)h;
    const short8* hb8 = (const short8*)hb;
    const int c8 = t & 15;
#pragma unroll
    for (int pass = 0; pass < 4; ++pass) {
        int nl = order[pass * 16 + (t >> 4)];
        int node = b * TSZ + nl;
        if (node >= NN) {
            short8 z = {0, 0, 0, 0, 0, 0, 0, 0};
            *(short8*)&xl[nl * 136 + c8 * 8] = z;
            continue;
        }
        float4 a0 = h4[node * 32 + c8 * 2];
        float4 a1 = h4[node * 32 + c8 * 2 + 1];
        float acc[8] = {sE * a0.x, sE * a0.y, sE * a0.z, sE * a0.w,
                        sE * a1.x, sE * a1.y, sE * a1.z, sE * a1.w};
        int e = beg64[nl], eend = beg64[nl] + cnt64[nl];
        if (HB) {
            for (; e + 3 < eend; e += 4) {
                int s0 = srcs[e], s1 = srcs[e + 1], s2 = srcs[e + 2], s3 = srcs[e + 3];
                short8 v0 = hb8[s0 * 16 + c8];
                short8 v1 = hb8[s1 * 16 + c8];
                short8 v2 = hb8[s2 * 16 + c8];
                short8 v3 = hb8[s3 * 16 + c8];
#pragma unroll
                for (int j = 0; j < 8; ++j) {
                    float t0 = bf2f((unsigned short)v0[j]) + bf2f((unsigned short)v1[j]);
                    float t1 = bf2f((unsigned short)v2[j]) + bf2f((unsigned short)v3[j]);
                    acc[j] += t0 + t1;
                }
            }
            for (; e < eend; ++e) {
                short8 v0 = hb8[srcs[e] * 16 + c8];
#pragma unroll
                for (int j = 0; j < 8; ++j) acc[j] += bf2f((unsigned short)v0[j]);
            }
        } else {
            for (; e + 1 < eend; e += 2) {
                int s0 = srcs[e], s1 = srcs[e + 1];
                float4 u0 = h4[s0 * 32 + c8 * 2], u1 = h4[s0 * 32 + c8 * 2 + 1];
                float4 w0 = h4[s1 * 32 + c8 * 2], w1 = h4[s1 * 32 + c8 * 2 + 1];
                acc[0] += u0.x + w0.x; acc[1] += u0.y + w0.y;
                acc[2] += u0.z + w0.z; acc[3] += u0.w + w0.w;
                acc[4] += u1.x + w1.x; acc[5] += u1.y + w1.y;
                acc[6] += u1.z + w1.z; acc[7] += u1.w + w1.w;
            }
            if (e < eend) {
                int s0 = srcs[e];
                float4 u0 = h4[s0 * 32 + c8 * 2], u1 = h4[s0 * 32 + c8 * 2 + 1];
                acc[0] += u0.x; acc[1] += u0.y; acc[2] += u0.z; acc[3] += u0.w;
                acc[4] += u1.x; acc[5] += u1.y; acc[6] += u1.z; acc[7] += u1.w;
            }
        }
        short8 o;
#pragma unroll
        for (int j = 0; j < 8; ++j) o[j] = (short)f2bf(acc[j]);
        *(short8*)&xl[nl * 136 + c8 * 8] = o;
    }
    __syncthreads();  // xl complete; offset scratch dead -> wl

    // ---- GEMM1: Y1 = relu(x@W1+b1), W half-staged ----
    floatx4 acc[8];
#pragma unroll
    for (int i = 0; i < 8; ++i) acc[i] = (floatx4){0.f, 0.f, 0.f, 0.f};
    const short8* W1t8 = (const short8*)W1t;
#pragma unroll
    for (int hh = 0; hh < 2; ++hh) {
#pragma unroll
        for (int l = 0; l < 4; ++l) {
            int idx = t + l * 256;
            int nr = idx >> 4, c = idx & 15;
            *(short8*)&wl[nr * 136 + c * 8] = W1t8[(hh * 64 + nr) * 16 + c];
        }
        __syncthreads();
#pragma unroll
        for (int kc = 0; kc < 4; ++kc) {
            short8 a = *(const short8*)&xl[(wv * 16 + m) * 136 + kc * 32 + hi * 8];
#pragma unroll
            for (int ntl = 0; ntl < 4; ++ntl) {
                short8 bb = *(const short8*)&wl[(ntl * 16 + m) * 136 + kc * 32 + hi * 8];
                acc[hh * 4 + ntl] =
                    __builtin_amdgcn_mfma_f32_16x16x32_bf16(a, bb, acc[hh * 4 + ntl], 0, 0, 0);
            }
        }
        __syncthreads();
    }
#pragma unroll
    for (int nt = 0; nt < 8; ++nt) {
        float bv = b1[nt * 16 + m];
#pragma unroll
        for (int r = 0; r < 4; ++r) {
            float v = fmaxf(acc[nt][r] + bv, 0.f);
            xl[(wv * 16 + hi * 4 + r) * 136 + nt * 16 + m] = f2bf(v);
        }
    }
    __syncthreads();

    // ---- GEMM2: Y2 = Y1@W2+b2 ----
#pragma unroll
    for (int i = 0; i < 8; ++i) acc[i] = (floatx4){0.f, 0.f, 0.f, 0.f};
    const short8* W2t8 = (const short8*)W2t;
#pragma unroll
    for (int hh = 0; hh < 2; ++hh) {
#pragma unroll
        for (int l = 0; l < 4; ++l) {
            int idx = t + l * 256;
            int nr = idx >> 4, c = idx & 15;
            *(short8*)&wl[nr * 136 + c * 8] = W2t8[(hh * 64 + nr) * 16 + c];
        }
        __syncthreads();
#pragma unroll
        for (int kc = 0; kc < 4; ++kc) {
            short8 a = *(const short8*)&xl[(wv * 16 + m) * 136 + kc * 32 + hi * 8];
#pragma unroll
            for (int ntl = 0; ntl < 4; ++ntl) {
                short8 bb = *(const short8*)&wl[(ntl * 16 + m) * 136 + kc * 32 + hi * 8];
                acc[hh * 4 + ntl] =
                    __builtin_amdgcn_mfma_f32_16x16x32_bf16(a, bb, acc[hh * 4 + ntl], 0, 0, 0);
            }
        }
        __syncthreads();
    }

    // ---- Y2 -> xl (bf16) + BN partials from f32 accumulators ----
#pragma unroll
    for (int nt = 0; nt < 8; ++nt) {
        float bv = b2[nt * 16 + m];
        float ss = 0.f, qq = 0.f;
#pragma unroll
        for (int r = 0; r < 4; ++r) {
            int row = wv * 16 + hi * 4 + r;
            float v = acc[nt][r] + bv;
            xl[row * 136 + nt * 16 + m] = f2bf(v);
            if (b * TSZ + row < NN) { ss += v; qq += v * v; }
        }
        sred[(nt * 16 + m) * 16 + wv * 4 + hi] = ss;
        qred[(nt * 16 + m) * 16 + wv * 4 + hi] = qq;
    }
    __syncthreads();

#pragma unroll
    for (int l = 0; l < 4; ++l) {
        int idx = t + l * 256;
        int row = idx >> 4, c = idx & 15;
        int g = b * TSZ + row;
        if (g < NN)
            ((short8*)Y)[g * 16 + c] = *(const short8*)&xl[row * 136 + c * 8];
    }
    if (t < 128) {
        float s = 0.f, q = 0.f;
#pragma unroll
        for (int j = 0; j < 16; ++j) { s += sred[t * 16 + j]; q += qred[t * 16 + j]; }
        atomicAdd(&stats[t], s);
        atomicAdd(&stats[DD + t], q);
    }
}

// ---------------------------------------------------------------------------
// K4: out = h + relu(Y*scale + shift). Column octet fixed per thread across
// the grid-stride loop -> BN math hoisted; Y read as short8.
// ---------------------------------------------------------------------------
__global__ __launch_bounds__(256) void bn_final_kernel(
    const unsigned short* __restrict__ Y, const float* __restrict__ h,
    const float* __restrict__ gamma, const float* __restrict__ beta,
    const float* __restrict__ stats, float* __restrict__ out)
{
    const float invN = 1.0f / (float)NN;
    int t0 = blockIdx.x * 256 + threadIdx.x;
    int c8 = t0 & 15;
    float sc[8], sh[8];
#pragma unroll
    for (int j = 0; j < 8; ++j) {
        int col = c8 * 8 + j;
        float mu = stats[col] * invN;
        float var = stats[DD + col] * invN - mu * mu;
        float s = rsqrtf(var + BN_EPS) * gamma[col];
        sc[j] = s;
        sh[j] = beta[col] - mu * s;
    }
    const short8* Y8 = (const short8*)Y;
    const float4* H4 = (const float4*)h;
    float4* O4 = (float4*)out;
    const int total = NN * 16;
    const int stride = BN_BLOCKS * 256;
    for (int i = t0; i < total; i += stride) {
        short8 u = Y8[i];
        float4 h0 = H4[2 * i], h1 = H4[2 * i + 1];
        float4 r0, r1;
        r0.x = h0.x + fmaxf(bf2f((unsigned short)u[0]) * sc[0] + sh[0], 0.f);
        r0.y = h0.y + fmaxf(bf2f((unsigned short)u[1]) * sc[1] + sh[1], 0.f);
        r0.z = h0.z + fmaxf(bf2f((unsigned short)u[2]) * sc[2] + sh[2], 0.f);
        r0.w = h0.w + fmaxf(bf2f((unsigned short)u[3]) * sc[3] + sh[3], 0.f);
        r1.x = h1.x + fmaxf(bf2f((unsigned short)u[4]) * sc[4] + sh[4], 0.f);
        r1.y = h1.y + fmaxf(bf2f((unsigned short)u[5]) * sc[5] + sh[5], 0.f);
        r1.z = h1.z + fmaxf(bf2f((unsigned short)u[6]) * sc[6] + sh[6], 0.f);
        r1.w = h1.w + fmaxf(bf2f((unsigned short)u[7]) * sc[7] + sh[7], 0.f);
        O4[2 * i] = r0;
        O4[2 * i + 1] = r1;
    }
}

// ---------------------------------------------------------------------------
extern "C" void kernel_launch(void* const* d_in, const int* in_sizes, int n_in,
                              void* d_out, int out_size, void* d_ws, size_t ws_size,
                              hipStream_t stream)
{
    const float* h     = (const float*)d_in[0];
    const int*   src   = (const int*)d_in[1];
    const int*   dst   = (const int*)d_in[2];
    const float* eps   = (const float*)d_in[3];
    const float* W1    = (const float*)d_in[4];
    const float* b1    = (const float*)d_in[5];
    const float* W2    = (const float*)d_in[6];
    const float* b2    = (const float*)d_in[7];
    const float* gamma = (const float*)d_in[8];
    const float* beta  = (const float*)d_in[9];
    float* out = (float*)d_out;

    char* w = (char*)d_ws;
    size_t o = 0;
    float* stats    = (float*)(w + o); o += 256 * 4;                 // zeroed by memset
    int* scnt       = (int*)(w + o); o += 256 * 4;                   // zeroed by memset
    unsigned short* W1t = (unsigned short*)(w + o); o += (size_t)DD * DD * 2;
    unsigned short* W2t = (unsigned short*)(w + o); o += (size_t)DD * DD * 2;
    int2* off2      = (int2*)(w + o); o += (size_t)NSB * SBSZ * 8;   // 802816
    int* sbuf       = (int*)(w + o); o += (size_t)NSB * CAPS * 4;    // 7.2 MB (reused as srcs)
    unsigned short* xb  = (unsigned short*)(w + o); o += (size_t)NN * DD * 2;
    unsigned short* hb  = (unsigned short*)(w + o); o += (size_t)NN * DD * 2;
    const int use_hb = (ws_size >= o) ? 1 : 0;  // launch-constant

    // 0. zero stats + super-bucket cursors (contiguous 2 KB)
    hipMemsetAsync(stats, 0, 512 * sizeof(int), stream);

    // 1. fused prep + pass-1 radix (line-granular, write-combined)
    prep_scatter_kernel<<<GRID_PS, 256, 0, stream>>>(
        W1, W2, W1t, W2t, h, hb, use_hb, src, dst, scnt, sbuf);

    // 2. pass-2 per-super-bucket CSR permute (single-writer 36KB regions)
    permute_kernel<<<NSB, 512, 0, stream>>>(scnt, sbuf, off2);

    // 3. gather + 2-layer MLP + BN stats (no permute phase)
    if (use_hb)
        gather_mlp_kernel<true><<<NTILE, 256, 0, stream>>>(
            h, hb, eps, off2, sbuf, W1t, W2t, b1, b2, xb, stats);
    else
        gather_mlp_kernel<false><<<NTILE, 256, 0, stream>>>(
            h, hb, eps, off2, sbuf, W1t, W2t, b1, b2, xb, stats);

    // 4. out = h + relu(BN(y2))
    bn_final_kernel<<<BN_BLOCKS, 256, 0, stream>>>(xb, h, gamma, beta, stats, out);
}